// Round 10
// baseline (1312.613 us; speedup 1.0000x reference)
//
#include <hip/hip_runtime.h>

#define EDGES 200000
#define NATOMS 100000
#define NMOLS 2000
#define H 128
#define MAXNB 15
#define AFD 18
#define INFD 23
#define LROW 136  // LDS A-tile row stride (bf16): +8 pad, 16B-aligned rows, 2-way banks
#define K1 32     // GEMM1 K (INFD=23 zero-padded to 32)
#define AROW 40   // GEMM1 LDS A-tile row stride (bf16 shorts)

// Precision ledger (measured):
//  R2: e4m3 tables -> err 448 (sat). R3/R4: e5m2 -> 1088/1120 (format-bound).
//  R5-R8: int8 per-32ch block-scale tables + e4m3 binput -> PASS.
//  R9: GEMM1 via bf16 MFMA -> PASS. R10: mechanics only, bit-identical.
// Mechanics ledger (measured):
//  R8: 8 lanes/row uint4 gather -> fusedq ~100us, FETCH 233MB == compulsory
//      floor (8 XCD x 25.6MB table replication + binput + bgraph).
//  R9: fusedq VALUBusy 42.7% (vs 21% in bf16 version) -> decode VALU throttles
//      gather issue; effective fetch rate 2.35 vs 3.6 TB/s.
//  R10: packed v_pk_fma_f32 decode (f32x2 exprs, contract=fast), 32-bit
//      voffset gathers (SGPR base), launch_bounds(128,8).

typedef unsigned short bf16s;
typedef unsigned char u8;
typedef __attribute__((ext_vector_type(8))) short short8;
typedef __attribute__((ext_vector_type(4))) float f32x4;
typedef __attribute__((ext_vector_type(2))) float f32x2;
typedef unsigned int uint4u __attribute__((ext_vector_type(4), aligned(4)));

__device__ inline float bf2f(bf16s u) {
  union { unsigned int i; float f; } c; c.i = ((unsigned int)u) << 16; return c.f;
}
__device__ inline bf16s f2bf(float f) {
  union { float f; unsigned int i; } c; c.f = f;
  unsigned int lsb = (c.i >> 16) & 1u;
  c.i += 0x7fffu + lsb;              // round-to-nearest-even
  return (bf16s)(c.i >> 16);
}
__device__ inline unsigned int pack2(f32x2 v) {
  return (unsigned int)f2bf(fmaxf(v.x, 0.f)) |
         ((unsigned int)f2bf(fmaxf(v.y, 0.f)) << 16);
}
// 16-lane max reduce on the VALU pipe via DPP row rotations (ror 1,2,4,8).
#define DPPMAX_STEP(m, CTRL)                                                   \
  {                                                                            \
    int _t = __builtin_amdgcn_update_dpp(                                      \
        0, __builtin_bit_cast(int, m), CTRL, 0xf, 0xf, false);                 \
    m = fmaxf(m, __builtin_bit_cast(float, _t));                               \
  }
__device__ inline float dpp_max16(float m) {
  DPPMAX_STEP(m, 0x121);  // row_ror:1
  DPPMAX_STEP(m, 0x122);  // row_ror:2
  DPPMAX_STEP(m, 0x124);  // row_ror:4
  DPPMAX_STEP(m, 0x128);  // row_ror:8
  return m;
}
// decode 4 packed u8 -> two f32x2, accumulate with packed fma (contract=fast)
__device__ inline void acc_word(f32x2& a0, f32x2& a1, unsigned w, f32x2 sj2) {
  f32x2 u01 = {(float)(w & 0xffu), (float)((w >> 8) & 0xffu)};
  f32x2 u23 = {(float)((w >> 16) & 0xffu), (float)(w >> 24)};
  a0 += sj2 * u01;
  a1 += sj2 * u23;
}

// ------- one-time transposed bf16 weights -------
// blk 0: wt_h[n][128] = Wh[k][n];  blk 1: wt_o[n][128] = Wo[AFD+k][n];
// blk 2: wt_i[n][32]  = Wi[k][n] (k<23; zero-pad 23..31)
__global__ __launch_bounds__(256) void k_wt(
    const float* __restrict__ Wh, const float* __restrict__ Wo,
    const float* __restrict__ Wi, bf16s* __restrict__ wt_h,
    bf16s* __restrict__ wt_o, bf16s* __restrict__ wt_i) {
  if (blockIdx.x == 2) {
    for (int i = threadIdx.x; i < H * K1; i += 256) {
      int n = i >> 5, k = i & 31;
      wt_i[i] = (k < INFD) ? f2bf(Wi[k * H + n]) : (bf16s)0;
    }
    return;
  }
  const float* S = blockIdx.x ? (Wo + AFD * H) : Wh;
  bf16s* D = blockIdx.x ? wt_o : wt_h;
  for (int i = threadIdx.x; i < H * H; i += 256) {
    int k = i >> 7, n = i & 127;
    D[n * H + k] = f2bf(S[i]);
  }
}

// MFMA epilogue: 16x128 @ 128x128 from wave-private LDS tile; q8 output:
// int8 payload rows [E][128] (aligned) + per-32ch bf16 scales in [E][4] Sout.
__device__ inline void mfma_epi_q8(const bf16s* Aw, const bf16s* __restrict__ Wt,
                                   u8* __restrict__ P8, bf16s* __restrict__ Sout,
                                   int ebase, int lane) {
  const int mm = lane & 15;
  const int quad = lane >> 4;
  const bf16s* Wp = Wt + (size_t)mm * H + quad * 8;
  const int rbase = ebase + quad * 4;
  f32x4 acc[2][4];
#pragma unroll
  for (int h = 0; h < 2; ++h)
#pragma unroll
    for (int i = 0; i < 4; ++i) acc[h][i] = (f32x4){0.f, 0.f, 0.f, 0.f};
#pragma unroll
  for (int kk = 0; kk < 4; ++kk) {
    short8 af = *(const short8*)&Aw[mm * LROW + quad * 8 + kk * 32];
#pragma unroll
    for (int h = 0; h < 2; ++h)
#pragma unroll
      for (int nt = 0; nt < 4; ++nt) {
        short8 bfr = *(const short8*)(Wp + (size_t)((h * 4 + nt) * 16) * H + kk * 32);
        acc[h][nt] = __builtin_amdgcn_mfma_f32_16x16x32_bf16(af, bfr, acc[h][nt], 0, 0, 0);
      }
  }
  // lane's channel c = (h*4+nt)*16+mm -> 32-ch block b = h*2 + (nt>>1)
  float m[4][4];  // [row i][block b] absmax
#pragma unroll
  for (int i = 0; i < 4; ++i)
#pragma unroll
    for (int b = 0; b < 4; ++b) m[i][b] = 0.f;
#pragma unroll
  for (int h = 0; h < 2; ++h)
#pragma unroll
    for (int nt = 0; nt < 4; ++nt) {
      const int b = h * 2 + (nt >> 1);
#pragma unroll
      for (int i = 0; i < 4; ++i) m[i][b] = fmaxf(m[i][b], fabsf(acc[h][nt][i]));
    }
#pragma unroll
  for (int i = 0; i < 4; ++i)
#pragma unroll
    for (int b = 0; b < 4; ++b) m[i][b] = dpp_max16(m[i][b]);
  float rs[4][4];
  unsigned short sbits[4][4];
#pragma unroll
  for (int i = 0; i < 4; ++i)
#pragma unroll
    for (int b = 0; b < 4; ++b) {
      bf16s sb = f2bf(m[i][b] * (1.f / 127.f));
      float sd = bf2f(sb);  // decode-exact scale
      rs[i][b] = sd > 0.f ? 1.f / sd : 0.f;
      sbits[i][b] = sb;
    }
  if (mm == 0) {
#pragma unroll
    for (int i = 0; i < 4; ++i) {
      ushort4 sv;
      sv.x = sbits[i][0]; sv.y = sbits[i][1];
      sv.z = sbits[i][2]; sv.w = sbits[i][3];
      *(ushort4*)&Sout[(size_t)(rbase + i) * 4] = sv;
    }
  }
#pragma unroll
  for (int h = 0; h < 2; ++h)
#pragma unroll
    for (int nt = 0; nt < 4; ++nt) {
      const int b = h * 2 + (nt >> 1);
#pragma unroll
      for (int i = 0; i < 4; ++i) {
        float q = fminf(fmaxf(acc[h][nt][i] * rs[i][b] + 128.5f, 0.f), 255.f);
        P8[(size_t)(rbase + i) * H + (h * 4 + nt) * 16 + mm] = (u8)(unsigned)q;
      }
    }
}

// ---- binput = fbonds @ W_i via MFMA (e4m3 out); M1 = relu(binput)@W_h (q8) ----
__global__ __launch_bounds__(256) void k_binput_gemm(
    const float* __restrict__ fbonds, const bf16s* __restrict__ wt_i,
    const bf16s* __restrict__ wt_h, u8* __restrict__ binput8,
    u8* __restrict__ P1, bf16s* __restrict__ S1) {
  __shared__ bf16s At[4][16 * AROW];
  __shared__ bf16s Am[4][16 * LROW];
  const int tid = threadIdx.x;
  const int wave = tid >> 6;
  const int lane = tid & 63;
  bf16s* A1 = At[wave];
  bf16s* Aw = Am[wave];
  const int ebase = (blockIdx.x * 4 + wave) * 16;

  // zero the A1 tile (covers the K=23..31 pad), then stage fbonds as bf16
  for (int i = lane; i < 16 * AROW / 2; i += 64) ((unsigned int*)A1)[i] = 0u;
  const float* fb = &fbonds[(size_t)ebase * INFD];
#pragma unroll
  for (int it = 0; it < 6; ++it) {
    int idx = it * 64 + lane;
    if (idx < 16 * INFD) {
      int er = idx / INFD;
      int k = idx - er * INFD;
      A1[er * AROW + k] = f2bf(fb[idx]);
    }
  }
  asm volatile("s_waitcnt lgkmcnt(0)" ::: "memory");

  const int mm = lane & 15;
  const int quad = lane >> 4;
  const int rbase = ebase + quad * 4;
  short8 af = *(const short8*)&A1[mm * AROW + quad * 8];
  const bf16s* Wp = wt_i + mm * K1 + quad * 8;
  f32x4 acc1[8];
#pragma unroll
  for (int nt = 0; nt < 8; ++nt) {
    short8 bfr = *(const short8*)(Wp + (size_t)(nt * 16) * K1);
    acc1[nt] = __builtin_amdgcn_mfma_f32_16x16x32_bf16(
        af, bfr, (f32x4){0.f, 0.f, 0.f, 0.f}, 0, 0, 0);
  }
  // binput8 e4m3 stores + relu->bf16 into GEMM2 A-tile
#pragma unroll
  for (int nt = 0; nt < 8; ++nt) {
#pragma unroll
    for (int i = 0; i < 4; ++i) {
      int d = __builtin_amdgcn_cvt_pk_fp8_f32(acc1[nt][i], acc1[nt][i], 0, false);
      binput8[(size_t)(rbase + i) * H + nt * 16 + mm] = (u8)(d & 0xff);
      Aw[(quad * 4 + i) * LROW + nt * 16 + mm] = f2bf(fmaxf(acc1[nt][i], 0.f));
    }
  }
  asm volatile("s_waitcnt lgkmcnt(0)" ::: "memory");
  mfma_epi_q8(Aw, wt_h, P1, S1, ebase, lane);
}

// ---- fused depth step: Pout = (relu(binput + sum_j P[bgraph[e][j]])) @ Wt ----
// All tables q8. 8 lanes x 16B (uint4) cover one 128B row; 2 outer iterations.
// 32-bit voffset gathers (SGPR base); packed-FMA decode (bit-identical).
__global__ __launch_bounds__(128, 8) void k_fusedq(
    const int* __restrict__ bgraph, const u8* __restrict__ P,
    const bf16s* __restrict__ Sin, const u8* __restrict__ binput8,
    const bf16s* __restrict__ Wt, u8* __restrict__ Pout,
    bf16s* __restrict__ Sout) {
  __shared__ bf16s Am[2][16 * LROW];
  const int tid = threadIdx.x;
  const int wave = tid >> 6;
  const int lane = tid & 63;
  bf16s* Aw = Am[wave];
  const int ebase = (blockIdx.x * 2 + wave) * 16;
  const u8* Sb = (const u8*)Sin;

  const int sub = lane >> 3;   // 8 rows per iteration
  const int col = lane & 7;    // 8 lanes x 16 channels = 128 cols
#pragma unroll
  for (int it = 0; it < 2; ++it) {
    const int erow = it * 8 + sub;
    const int e = ebase + erow;
    const int* bg = &bgraph[(size_t)e * MAXNB];
    uint4u i0 = *(const uint4u*)(bg + 0);
    uint4u i1 = *(const uint4u*)(bg + 4);
    uint4u i2 = *(const uint4u*)(bg + 8);
    int idx[MAXNB];
    idx[0] = i0.x; idx[1] = i0.y; idx[2] = i0.z; idx[3] = i0.w;
    idx[4] = i1.x; idx[5] = i1.y; idx[6] = i1.z; idx[7] = i1.w;
    idx[8] = i2.x; idx[9] = i2.y; idx[10] = i2.z; idx[11] = i2.w;
    idx[12] = bg[12]; idx[13] = bg[13]; idx[14] = bg[14];

    uint4 t[MAXNB];
    float s[MAXNB];
#pragma unroll
    for (int j = 0; j < MAXNB; ++j) {
      t[j] = *(const uint4*)(P + (size_t)(unsigned)((idx[j] << 7) + col * 16));
      s[j] = bf2f(*(const bf16s*)(Sb + (size_t)(unsigned)((idx[j] << 3) + (col >> 1) * 2)));
    }
    uint4 bi = *(const uint4*)(binput8 + (size_t)(unsigned)((e << 7) + col * 16));
    f32x2 acc[8];
    acc[0] = __builtin_amdgcn_cvt_pk_f32_fp8(bi.x, false);
    acc[1] = __builtin_amdgcn_cvt_pk_f32_fp8(bi.x, true);
    acc[2] = __builtin_amdgcn_cvt_pk_f32_fp8(bi.y, false);
    acc[3] = __builtin_amdgcn_cvt_pk_f32_fp8(bi.y, true);
    acc[4] = __builtin_amdgcn_cvt_pk_f32_fp8(bi.z, false);
    acc[5] = __builtin_amdgcn_cvt_pk_f32_fp8(bi.z, true);
    acc[6] = __builtin_amdgcn_cvt_pk_f32_fp8(bi.w, false);
    acc[7] = __builtin_amdgcn_cvt_pk_f32_fp8(bi.w, true);
    float ssum = 0.f;
#pragma unroll
    for (int j = 0; j < MAXNB; ++j) ssum += s[j];
#pragma unroll
    for (int j = 0; j < MAXNB; ++j) {
      const f32x2 sj2 = {s[j], s[j]};
      acc_word(acc[0], acc[1], t[j].x, sj2);
      acc_word(acc[2], acc[3], t[j].y, sj2);
      acc_word(acc[4], acc[5], t[j].z, sj2);
      acc_word(acc[6], acc[7], t[j].w, sj2);
    }
    const f32x2 off = {128.f * ssum, 128.f * ssum};
#pragma unroll
    for (int k = 0; k < 8; ++k) acc[k] -= off;
    uint4 o0, o1;
    o0.x = pack2(acc[0]); o0.y = pack2(acc[1]);
    o0.z = pack2(acc[2]); o0.w = pack2(acc[3]);
    o1.x = pack2(acc[4]); o1.y = pack2(acc[5]);
    o1.z = pack2(acc[6]); o1.w = pack2(acc[7]);
    *(uint4*)&Aw[erow * LROW + col * 16] = o0;
    *(uint4*)&Aw[erow * LROW + col * 16 + 8] = o1;
  }
  asm volatile("s_waitcnt lgkmcnt(0)" ::: "memory");
  mfma_epi_q8(Aw, Wt, Pout, Sout, ebase, lane);
}

// atom_hiddens = relu(fatoms @ Wo[0:18] + sum_j msg[agraph[a][j]] + b_o)
// q8 gather, 8 lanes x 16 channels per atom; 32 atoms per 256-thread block.
__global__ __launch_bounds__(256, 4) void k_atoms(
    const float* __restrict__ fatoms, const int* __restrict__ agraph,
    const u8* __restrict__ msgQ, const bf16s* __restrict__ msgS,
    const float* __restrict__ Wo, const float* __restrict__ bo,
    bf16s* __restrict__ atomh) {
  __shared__ float Wl[AFD * H];
  const int tid = threadIdx.x;
  for (int i = tid; i < AFD * H; i += 256) Wl[i] = Wo[i];
  __syncthreads();
  const int col = tid & 7;
  const int a = blockIdx.x * 32 + (tid >> 3);
  const u8* Sb = (const u8*)msgS;
  const int* ag = &agraph[(size_t)a * MAXNB];
  uint4u i0 = *(const uint4u*)(ag + 0);
  uint4u i1 = *(const uint4u*)(ag + 4);
  uint4u i2 = *(const uint4u*)(ag + 8);
  int idx[MAXNB];
  idx[0] = i0.x; idx[1] = i0.y; idx[2] = i0.z; idx[3] = i0.w;
  idx[4] = i1.x; idx[5] = i1.y; idx[6] = i1.z; idx[7] = i1.w;
  idx[8] = i2.x; idx[9] = i2.y; idx[10] = i2.z; idx[11] = i2.w;
  idx[12] = ag[12]; idx[13] = ag[13]; idx[14] = ag[14];
  uint4 t[MAXNB];
  float s[MAXNB];
#pragma unroll
  for (int j = 0; j < MAXNB; ++j) {
    t[j] = *(const uint4*)(msgQ + (size_t)(unsigned)((idx[j] << 7) + col * 16));
    s[j] = bf2f(*(const bf16s*)(Sb + (size_t)(unsigned)((idx[j] << 3) + (col >> 1) * 2)));
  }
  f32x2 acc[8];
#pragma unroll
  for (int k = 0; k < 4; ++k) {
    float4 b = ((const float4*)bo)[col * 4 + k];
    acc[2 * k] = (f32x2){b.x, b.y};
    acc[2 * k + 1] = (f32x2){b.z, b.w};
  }
#pragma unroll
  for (int k = 0; k < AFD; ++k) {
    float f = fatoms[(size_t)a * AFD + k];
    const f32x2 f2 = {f, f};
#pragma unroll
    for (int q = 0; q < 4; ++q) {
      float4 w = ((const float4*)&Wl[k * H + col * 16])[q];
      acc[2 * q] += f2 * (f32x2){w.x, w.y};
      acc[2 * q + 1] += f2 * (f32x2){w.z, w.w};
    }
  }
  float ssum = 0.f;
#pragma unroll
  for (int j = 0; j < MAXNB; ++j) ssum += s[j];
#pragma unroll
  for (int j = 0; j < MAXNB; ++j) {
    const f32x2 sj2 = {s[j], s[j]};
    acc_word(acc[0], acc[1], t[j].x, sj2);
    acc_word(acc[2], acc[3], t[j].y, sj2);
    acc_word(acc[4], acc[5], t[j].z, sj2);
    acc_word(acc[6], acc[7], t[j].w, sj2);
  }
  const f32x2 off = {128.f * ssum, 128.f * ssum};
#pragma unroll
  for (int k = 0; k < 8; ++k) acc[k] -= off;
  uint4 o0, o1;
  o0.x = pack2(acc[0]); o0.y = pack2(acc[1]);
  o0.z = pack2(acc[2]); o0.w = pack2(acc[3]);
  o1.x = pack2(acc[4]); o1.y = pack2(acc[5]);
  o1.z = pack2(acc[6]); o1.w = pack2(acc[7]);
  *(uint4*)&atomh[(size_t)a * H + col * 16] = o0;
  *(uint4*)&atomh[(size_t)a * H + col * 16 + 8] = o1;
}

// ---------------- segment mean pool (bf16 in, f32 out) ----------------
__global__ void k_pool(const bf16s* __restrict__ atomh,
                       const int* __restrict__ sstart, const int* __restrict__ slen,
                       float* __restrict__ out) {
  const int m = blockIdx.x;
  const int c = threadIdx.x;
  const int s = sstart[m];
  const int L = slen[m];
  float sum = 0.f;
  for (int i = 0; i < L; ++i) sum += bf2f(atomh[(size_t)(s + i) * H + c]);
  out[m * H + c] = sum / (float)L;
}

extern "C" void kernel_launch(void* const* d_in, const int* in_sizes, int n_in,
                              void* d_out, int out_size, void* d_ws, size_t ws_size,
                              hipStream_t stream) {
  const float* fatoms = (const float*)d_in[0];
  const float* fbonds = (const float*)d_in[1];
  const int* agraph = (const int*)d_in[2];
  const int* bgraph = (const int*)d_in[3];
  const int* sstart = (const int*)d_in[4];
  const int* slen = (const int*)d_in[5];
  const float* Wi = (const float*)d_in[6];
  const float* Wh = (const float*)d_in[7];
  const float* Wo = (const float*)d_in[8];
  const float* bo = (const float*)d_in[9];
  float* out = (float*)d_out;

  const size_t EH = (size_t)EDGES * H;   // 25.6M bytes for q8 tables
  // Workspace (~81 MB of the budget):
  //  [0,    EH) binput8 e4m3 (dead after M6; atomh bf16 = NATOMS*H*2 = EH overlays)
  //  [EH,  2EH) QA payload | [2EH, 3EH) QB payload
  //  [3EH, ...) SA scales (1.6MB) | SB scales (1.6MB)
  char* W = (char*)d_ws;
  u8*    binput8 = (u8*)W;
  u8*    QA = (u8*)(W + EH);
  u8*    QB = (u8*)(W + 2 * EH);
  bf16s* SA = (bf16s*)(W + 3 * EH);
  bf16s* SB = (bf16s*)(W + 3 * EH + (size_t)EDGES * 8);
  bf16s* atomh = (bf16s*)W;
  bf16s* wt_h = (bf16s*)d_out;   // stashed in d_out; k_pool overwrites later
  bf16s* wt_o = wt_h + H * H;
  bf16s* wt_i = wt_o + H * H;

  k_wt<<<3, 256, 0, stream>>>(Wh, Wo, Wi, wt_h, wt_o, wt_i);
  k_binput_gemm<<<EDGES / 64, 256, 0, stream>>>(fbonds, wt_i, wt_h, binput8, QA, SA); // M1
  k_fusedq<<<EDGES / 32, 128, 0, stream>>>(bgraph, QA, SA, binput8, wt_h, QB, SB);    // M2
  k_fusedq<<<EDGES / 32, 128, 0, stream>>>(bgraph, QB, SB, binput8, wt_h, QA, SA);    // M3
  k_fusedq<<<EDGES / 32, 128, 0, stream>>>(bgraph, QA, SA, binput8, wt_h, QB, SB);    // M4
  k_fusedq<<<EDGES / 32, 128, 0, stream>>>(bgraph, QB, SB, binput8, wt_h, QA, SA);    // M5
  k_fusedq<<<EDGES / 32, 128, 0, stream>>>(bgraph, QA, SA, binput8, wt_o, QB, SB);    // M6
  k_atoms<<<NATOMS / 32, 256, 0, stream>>>(fatoms, agraph, QB, SB, Wo, bo, atomh);
  k_pool<<<NMOLS, H, 0, stream>>>(atomh, sstart, slen, out);
}

// Round 11
// 723.983 us; speedup vs baseline: 1.8130x; 1.8130x over previous
//
#include <hip/hip_runtime.h>

#define EDGES 200000
#define NATOMS 100000
#define NMOLS 2000
#define H 128
#define MAXNB 15
#define AFD 18
#define INFD 23
#define LROW 136  // LDS A-tile row stride (bf16): +8 pad, 16B-aligned rows, 2-way banks
#define K1 32     // GEMM1 K (INFD=23 zero-padded to 32)
#define AROW 40   // GEMM1 LDS A-tile row stride (bf16 shorts)

// Precision ledger (measured):
//  R2: e4m3 tables -> err 448 (sat). R3/R4: e5m2 -> 1088/1120 (format-bound).
//  R5-R8: int8 per-32ch block-scale tables + e4m3 binput -> PASS.
//  R9: GEMM1 via bf16 MFMA -> PASS err 128.
// Mechanics ledger (measured):
//  R8: 8 lanes/row uint4 gather -> fusedq ~100us, FETCH 233MB == compulsory
//      floor (8 XCD x 25.6MB table replication + binput + bgraph).
//  R10: __launch_bounds__(128,8) -> VGPR squeezed to 32, SCRATCH SPILL
//      (WRITE 380MB, FETCH 464MB), 2.2x regression. NEVER cap below the
//      kernel's live set (~90 VGPR: 15x uint4 + scales + accs).
//  R11: revert to (128,4); keep packed v_pk_fma decode + 32-bit voffset.

typedef unsigned short bf16s;
typedef unsigned char u8;
typedef __attribute__((ext_vector_type(8))) short short8;
typedef __attribute__((ext_vector_type(4))) float f32x4;
typedef __attribute__((ext_vector_type(2))) float f32x2;
typedef unsigned int uint4u __attribute__((ext_vector_type(4), aligned(4)));

__device__ inline float bf2f(bf16s u) {
  union { unsigned int i; float f; } c; c.i = ((unsigned int)u) << 16; return c.f;
}
__device__ inline bf16s f2bf(float f) {
  union { float f; unsigned int i; } c; c.f = f;
  unsigned int lsb = (c.i >> 16) & 1u;
  c.i += 0x7fffu + lsb;              // round-to-nearest-even
  return (bf16s)(c.i >> 16);
}
__device__ inline unsigned int pack2(f32x2 v) {
  return (unsigned int)f2bf(fmaxf(v.x, 0.f)) |
         ((unsigned int)f2bf(fmaxf(v.y, 0.f)) << 16);
}
// 16-lane max reduce on the VALU pipe via DPP row rotations (ror 1,2,4,8).
#define DPPMAX_STEP(m, CTRL)                                                   \
  {                                                                            \
    int _t = __builtin_amdgcn_update_dpp(                                      \
        0, __builtin_bit_cast(int, m), CTRL, 0xf, 0xf, false);                 \
    m = fmaxf(m, __builtin_bit_cast(float, _t));                               \
  }
__device__ inline float dpp_max16(float m) {
  DPPMAX_STEP(m, 0x121);  // row_ror:1
  DPPMAX_STEP(m, 0x122);  // row_ror:2
  DPPMAX_STEP(m, 0x124);  // row_ror:4
  DPPMAX_STEP(m, 0x128);  // row_ror:8
  return m;
}
// decode 4 packed u8 -> two f32x2, accumulate with packed fma (contract=fast)
__device__ inline void acc_word(f32x2& a0, f32x2& a1, unsigned w, f32x2 sj2) {
  f32x2 u01 = {(float)(w & 0xffu), (float)((w >> 8) & 0xffu)};
  f32x2 u23 = {(float)((w >> 16) & 0xffu), (float)(w >> 24)};
  a0 += sj2 * u01;
  a1 += sj2 * u23;
}

// ------- one-time transposed bf16 weights -------
// blk 0: wt_h[n][128] = Wh[k][n];  blk 1: wt_o[n][128] = Wo[AFD+k][n];
// blk 2: wt_i[n][32]  = Wi[k][n] (k<23; zero-pad 23..31)
__global__ __launch_bounds__(256) void k_wt(
    const float* __restrict__ Wh, const float* __restrict__ Wo,
    const float* __restrict__ Wi, bf16s* __restrict__ wt_h,
    bf16s* __restrict__ wt_o, bf16s* __restrict__ wt_i) {
  if (blockIdx.x == 2) {
    for (int i = threadIdx.x; i < H * K1; i += 256) {
      int n = i >> 5, k = i & 31;
      wt_i[i] = (k < INFD) ? f2bf(Wi[k * H + n]) : (bf16s)0;
    }
    return;
  }
  const float* S = blockIdx.x ? (Wo + AFD * H) : Wh;
  bf16s* D = blockIdx.x ? wt_o : wt_h;
  for (int i = threadIdx.x; i < H * H; i += 256) {
    int k = i >> 7, n = i & 127;
    D[n * H + k] = f2bf(S[i]);
  }
}

// MFMA epilogue: 16x128 @ 128x128 from wave-private LDS tile; q8 output:
// int8 payload rows [E][128] (aligned) + per-32ch bf16 scales in [E][4] Sout.
__device__ inline void mfma_epi_q8(const bf16s* Aw, const bf16s* __restrict__ Wt,
                                   u8* __restrict__ P8, bf16s* __restrict__ Sout,
                                   int ebase, int lane) {
  const int mm = lane & 15;
  const int quad = lane >> 4;
  const bf16s* Wp = Wt + (size_t)mm * H + quad * 8;
  const int rbase = ebase + quad * 4;
  f32x4 acc[2][4];
#pragma unroll
  for (int h = 0; h < 2; ++h)
#pragma unroll
    for (int i = 0; i < 4; ++i) acc[h][i] = (f32x4){0.f, 0.f, 0.f, 0.f};
#pragma unroll
  for (int kk = 0; kk < 4; ++kk) {
    short8 af = *(const short8*)&Aw[mm * LROW + quad * 8 + kk * 32];
#pragma unroll
    for (int h = 0; h < 2; ++h)
#pragma unroll
      for (int nt = 0; nt < 4; ++nt) {
        short8 bfr = *(const short8*)(Wp + (size_t)((h * 4 + nt) * 16) * H + kk * 32);
        acc[h][nt] = __builtin_amdgcn_mfma_f32_16x16x32_bf16(af, bfr, acc[h][nt], 0, 0, 0);
      }
  }
  // lane's channel c = (h*4+nt)*16+mm -> 32-ch block b = h*2 + (nt>>1)
  float m[4][4];  // [row i][block b] absmax
#pragma unroll
  for (int i = 0; i < 4; ++i)
#pragma unroll
    for (int b = 0; b < 4; ++b) m[i][b] = 0.f;
#pragma unroll
  for (int h = 0; h < 2; ++h)
#pragma unroll
    for (int nt = 0; nt < 4; ++nt) {
      const int b = h * 2 + (nt >> 1);
#pragma unroll
      for (int i = 0; i < 4; ++i) m[i][b] = fmaxf(m[i][b], fabsf(acc[h][nt][i]));
    }
#pragma unroll
  for (int i = 0; i < 4; ++i)
#pragma unroll
    for (int b = 0; b < 4; ++b) m[i][b] = dpp_max16(m[i][b]);
  float rs[4][4];
  unsigned short sbits[4][4];
#pragma unroll
  for (int i = 0; i < 4; ++i)
#pragma unroll
    for (int b = 0; b < 4; ++b) {
      bf16s sb = f2bf(m[i][b] * (1.f / 127.f));
      float sd = bf2f(sb);  // decode-exact scale
      rs[i][b] = sd > 0.f ? 1.f / sd : 0.f;
      sbits[i][b] = sb;
    }
  if (mm == 0) {
#pragma unroll
    for (int i = 0; i < 4; ++i) {
      ushort4 sv;
      sv.x = sbits[i][0]; sv.y = sbits[i][1];
      sv.z = sbits[i][2]; sv.w = sbits[i][3];
      *(ushort4*)&Sout[(size_t)(rbase + i) * 4] = sv;
    }
  }
#pragma unroll
  for (int h = 0; h < 2; ++h)
#pragma unroll
    for (int nt = 0; nt < 4; ++nt) {
      const int b = h * 2 + (nt >> 1);
#pragma unroll
      for (int i = 0; i < 4; ++i) {
        float q = fminf(fmaxf(acc[h][nt][i] * rs[i][b] + 128.5f, 0.f), 255.f);
        P8[(size_t)(rbase + i) * H + (h * 4 + nt) * 16 + mm] = (u8)(unsigned)q;
      }
    }
}

// ---- binput = fbonds @ W_i via MFMA (e4m3 out); M1 = relu(binput)@W_h (q8) ----
__global__ __launch_bounds__(256) void k_binput_gemm(
    const float* __restrict__ fbonds, const bf16s* __restrict__ wt_i,
    const bf16s* __restrict__ wt_h, u8* __restrict__ binput8,
    u8* __restrict__ P1, bf16s* __restrict__ S1) {
  __shared__ bf16s At[4][16 * AROW];
  __shared__ bf16s Am[4][16 * LROW];
  const int tid = threadIdx.x;
  const int wave = tid >> 6;
  const int lane = tid & 63;
  bf16s* A1 = At[wave];
  bf16s* Aw = Am[wave];
  const int ebase = (blockIdx.x * 4 + wave) * 16;

  // zero the A1 tile (covers the K=23..31 pad), then stage fbonds as bf16
  for (int i = lane; i < 16 * AROW / 2; i += 64) ((unsigned int*)A1)[i] = 0u;
  const float* fb = &fbonds[(size_t)ebase * INFD];
#pragma unroll
  for (int it = 0; it < 6; ++it) {
    int idx = it * 64 + lane;
    if (idx < 16 * INFD) {
      int er = idx / INFD;
      int k = idx - er * INFD;
      A1[er * AROW + k] = f2bf(fb[idx]);
    }
  }
  asm volatile("s_waitcnt lgkmcnt(0)" ::: "memory");

  const int mm = lane & 15;
  const int quad = lane >> 4;
  const int rbase = ebase + quad * 4;
  short8 af = *(const short8*)&A1[mm * AROW + quad * 8];
  const bf16s* Wp = wt_i + mm * K1 + quad * 8;
  f32x4 acc1[8];
#pragma unroll
  for (int nt = 0; nt < 8; ++nt) {
    short8 bfr = *(const short8*)(Wp + (size_t)(nt * 16) * K1);
    acc1[nt] = __builtin_amdgcn_mfma_f32_16x16x32_bf16(
        af, bfr, (f32x4){0.f, 0.f, 0.f, 0.f}, 0, 0, 0);
  }
  // binput8 e4m3 stores + relu->bf16 into GEMM2 A-tile
#pragma unroll
  for (int nt = 0; nt < 8; ++nt) {
#pragma unroll
    for (int i = 0; i < 4; ++i) {
      int d = __builtin_amdgcn_cvt_pk_fp8_f32(acc1[nt][i], acc1[nt][i], 0, false);
      binput8[(size_t)(rbase + i) * H + nt * 16 + mm] = (u8)(d & 0xff);
      Aw[(quad * 4 + i) * LROW + nt * 16 + mm] = f2bf(fmaxf(acc1[nt][i], 0.f));
    }
  }
  asm volatile("s_waitcnt lgkmcnt(0)" ::: "memory");
  mfma_epi_q8(Aw, wt_h, P1, S1, ebase, lane);
}

// ---- fused depth step: Pout = (relu(binput + sum_j P[bgraph[e][j]])) @ Wt ----
// All tables q8. 8 lanes x 16B (uint4) cover one 128B row; 2 outer iterations.
// 32-bit voffset gathers (SGPR base); packed-FMA decode (bit-identical).
// launch_bounds (128,4): 128-VGPR cap -- the live set (~90) must fit (R10!).
__global__ __launch_bounds__(128, 4) void k_fusedq(
    const int* __restrict__ bgraph, const u8* __restrict__ P,
    const bf16s* __restrict__ Sin, const u8* __restrict__ binput8,
    const bf16s* __restrict__ Wt, u8* __restrict__ Pout,
    bf16s* __restrict__ Sout) {
  __shared__ bf16s Am[2][16 * LROW];
  const int tid = threadIdx.x;
  const int wave = tid >> 6;
  const int lane = tid & 63;
  bf16s* Aw = Am[wave];
  const int ebase = (blockIdx.x * 2 + wave) * 16;
  const u8* Sb = (const u8*)Sin;

  const int sub = lane >> 3;   // 8 rows per iteration
  const int col = lane & 7;    // 8 lanes x 16 channels = 128 cols
#pragma unroll
  for (int it = 0; it < 2; ++it) {
    const int erow = it * 8 + sub;
    const int e = ebase + erow;
    const int* bg = &bgraph[(size_t)e * MAXNB];
    uint4u i0 = *(const uint4u*)(bg + 0);
    uint4u i1 = *(const uint4u*)(bg + 4);
    uint4u i2 = *(const uint4u*)(bg + 8);
    int idx[MAXNB];
    idx[0] = i0.x; idx[1] = i0.y; idx[2] = i0.z; idx[3] = i0.w;
    idx[4] = i1.x; idx[5] = i1.y; idx[6] = i1.z; idx[7] = i1.w;
    idx[8] = i2.x; idx[9] = i2.y; idx[10] = i2.z; idx[11] = i2.w;
    idx[12] = bg[12]; idx[13] = bg[13]; idx[14] = bg[14];

    uint4 t[MAXNB];
    float s[MAXNB];
#pragma unroll
    for (int j = 0; j < MAXNB; ++j) {
      t[j] = *(const uint4*)(P + (size_t)(unsigned)((idx[j] << 7) + col * 16));
      s[j] = bf2f(*(const bf16s*)(Sb + (size_t)(unsigned)((idx[j] << 3) + (col >> 1) * 2)));
    }
    uint4 bi = *(const uint4*)(binput8 + (size_t)(unsigned)((e << 7) + col * 16));
    f32x2 acc[8];
    acc[0] = __builtin_amdgcn_cvt_pk_f32_fp8(bi.x, false);
    acc[1] = __builtin_amdgcn_cvt_pk_f32_fp8(bi.x, true);
    acc[2] = __builtin_amdgcn_cvt_pk_f32_fp8(bi.y, false);
    acc[3] = __builtin_amdgcn_cvt_pk_f32_fp8(bi.y, true);
    acc[4] = __builtin_amdgcn_cvt_pk_f32_fp8(bi.z, false);
    acc[5] = __builtin_amdgcn_cvt_pk_f32_fp8(bi.z, true);
    acc[6] = __builtin_amdgcn_cvt_pk_f32_fp8(bi.w, false);
    acc[7] = __builtin_amdgcn_cvt_pk_f32_fp8(bi.w, true);
    float ssum = 0.f;
#pragma unroll
    for (int j = 0; j < MAXNB; ++j) ssum += s[j];
#pragma unroll
    for (int j = 0; j < MAXNB; ++j) {
      const f32x2 sj2 = {s[j], s[j]};
      acc_word(acc[0], acc[1], t[j].x, sj2);
      acc_word(acc[2], acc[3], t[j].y, sj2);
      acc_word(acc[4], acc[5], t[j].z, sj2);
      acc_word(acc[6], acc[7], t[j].w, sj2);
    }
    const f32x2 off = {128.f * ssum, 128.f * ssum};
#pragma unroll
    for (int k = 0; k < 8; ++k) acc[k] -= off;
    uint4 o0, o1;
    o0.x = pack2(acc[0]); o0.y = pack2(acc[1]);
    o0.z = pack2(acc[2]); o0.w = pack2(acc[3]);
    o1.x = pack2(acc[4]); o1.y = pack2(acc[5]);
    o1.z = pack2(acc[6]); o1.w = pack2(acc[7]);
    *(uint4*)&Aw[erow * LROW + col * 16] = o0;
    *(uint4*)&Aw[erow * LROW + col * 16 + 8] = o1;
  }
  asm volatile("s_waitcnt lgkmcnt(0)" ::: "memory");
  mfma_epi_q8(Aw, Wt, Pout, Sout, ebase, lane);
}

// atom_hiddens = relu(fatoms @ Wo[0:18] + sum_j msg[agraph[a][j]] + b_o)
// q8 gather, 8 lanes x 16 channels per atom; 32 atoms per 256-thread block.
__global__ __launch_bounds__(256, 4) void k_atoms(
    const float* __restrict__ fatoms, const int* __restrict__ agraph,
    const u8* __restrict__ msgQ, const bf16s* __restrict__ msgS,
    const float* __restrict__ Wo, const float* __restrict__ bo,
    bf16s* __restrict__ atomh) {
  __shared__ float Wl[AFD * H];
  const int tid = threadIdx.x;
  for (int i = tid; i < AFD * H; i += 256) Wl[i] = Wo[i];
  __syncthreads();
  const int col = tid & 7;
  const int a = blockIdx.x * 32 + (tid >> 3);
  const u8* Sb = (const u8*)msgS;
  const int* ag = &agraph[(size_t)a * MAXNB];
  uint4u i0 = *(const uint4u*)(ag + 0);
  uint4u i1 = *(const uint4u*)(ag + 4);
  uint4u i2 = *(const uint4u*)(ag + 8);
  int idx[MAXNB];
  idx[0] = i0.x; idx[1] = i0.y; idx[2] = i0.z; idx[3] = i0.w;
  idx[4] = i1.x; idx[5] = i1.y; idx[6] = i1.z; idx[7] = i1.w;
  idx[8] = i2.x; idx[9] = i2.y; idx[10] = i2.z; idx[11] = i2.w;
  idx[12] = ag[12]; idx[13] = ag[13]; idx[14] = ag[14];
  uint4 t[MAXNB];
  float s[MAXNB];
#pragma unroll
  for (int j = 0; j < MAXNB; ++j) {
    t[j] = *(const uint4*)(msgQ + (size_t)(unsigned)((idx[j] << 7) + col * 16));
    s[j] = bf2f(*(const bf16s*)(Sb + (size_t)(unsigned)((idx[j] << 3) + (col >> 1) * 2)));
  }
  f32x2 acc[8];
#pragma unroll
  for (int k = 0; k < 4; ++k) {
    float4 b = ((const float4*)bo)[col * 4 + k];
    acc[2 * k] = (f32x2){b.x, b.y};
    acc[2 * k + 1] = (f32x2){b.z, b.w};
  }
#pragma unroll
  for (int k = 0; k < AFD; ++k) {
    float f = fatoms[(size_t)a * AFD + k];
    const f32x2 f2 = {f, f};
#pragma unroll
    for (int q = 0; q < 4; ++q) {
      float4 w = ((const float4*)&Wl[k * H + col * 16])[q];
      acc[2 * q] += f2 * (f32x2){w.x, w.y};
      acc[2 * q + 1] += f2 * (f32x2){w.z, w.w};
    }
  }
  float ssum = 0.f;
#pragma unroll
  for (int j = 0; j < MAXNB; ++j) ssum += s[j];
#pragma unroll
  for (int j = 0; j < MAXNB; ++j) {
    const f32x2 sj2 = {s[j], s[j]};
    acc_word(acc[0], acc[1], t[j].x, sj2);
    acc_word(acc[2], acc[3], t[j].y, sj2);
    acc_word(acc[4], acc[5], t[j].z, sj2);
    acc_word(acc[6], acc[7], t[j].w, sj2);
  }
  const f32x2 off = {128.f * ssum, 128.f * ssum};
#pragma unroll
  for (int k = 0; k < 8; ++k) acc[k] -= off;
  uint4 o0, o1;
  o0.x = pack2(acc[0]); o0.y = pack2(acc[1]);
  o0.z = pack2(acc[2]); o0.w = pack2(acc[3]);
  o1.x = pack2(acc[4]); o1.y = pack2(acc[5]);
  o1.z = pack2(acc[6]); o1.w = pack2(acc[7]);
  *(uint4*)&atomh[(size_t)a * H + col * 16] = o0;
  *(uint4*)&atomh[(size_t)a * H + col * 16 + 8] = o1;
}

// ---------------- segment mean pool (bf16 in, f32 out) ----------------
__global__ void k_pool(const bf16s* __restrict__ atomh,
                       const int* __restrict__ sstart, const int* __restrict__ slen,
                       float* __restrict__ out) {
  const int m = blockIdx.x;
  const int c = threadIdx.x;
  const int s = sstart[m];
  const int L = slen[m];
  float sum = 0.f;
  for (int i = 0; i < L; ++i) sum += bf2f(atomh[(size_t)(s + i) * H + c]);
  out[m * H + c] = sum / (float)L;
}

extern "C" void kernel_launch(void* const* d_in, const int* in_sizes, int n_in,
                              void* d_out, int out_size, void* d_ws, size_t ws_size,
                              hipStream_t stream) {
  const float* fatoms = (const float*)d_in[0];
  const float* fbonds = (const float*)d_in[1];
  const int* agraph = (const int*)d_in[2];
  const int* bgraph = (const int*)d_in[3];
  const int* sstart = (const int*)d_in[4];
  const int* slen = (const int*)d_in[5];
  const float* Wi = (const float*)d_in[6];
  const float* Wh = (const float*)d_in[7];
  const float* Wo = (const float*)d_in[8];
  const float* bo = (const float*)d_in[9];
  float* out = (float*)d_out;

  const size_t EH = (size_t)EDGES * H;   // 25.6M bytes for q8 tables
  // Workspace (~81 MB of the budget):
  //  [0,    EH) binput8 e4m3 (dead after M6; atomh bf16 = NATOMS*H*2 = EH overlays)
  //  [EH,  2EH) QA payload | [2EH, 3EH) QB payload
  //  [3EH, ...) SA scales (1.6MB) | SB scales (1.6MB)
  char* W = (char*)d_ws;
  u8*    binput8 = (u8*)W;
  u8*    QA = (u8*)(W + EH);
  u8*    QB = (u8*)(W + 2 * EH);
  bf16s* SA = (bf16s*)(W + 3 * EH);
  bf16s* SB = (bf16s*)(W + 3 * EH + (size_t)EDGES * 8);
  bf16s* atomh = (bf16s*)W;
  bf16s* wt_h = (bf16s*)d_out;   // stashed in d_out; k_pool overwrites later
  bf16s* wt_o = wt_h + H * H;
  bf16s* wt_i = wt_o + H * H;

  k_wt<<<3, 256, 0, stream>>>(Wh, Wo, Wi, wt_h, wt_o, wt_i);
  k_binput_gemm<<<EDGES / 64, 256, 0, stream>>>(fbonds, wt_i, wt_h, binput8, QA, SA); // M1
  k_fusedq<<<EDGES / 32, 128, 0, stream>>>(bgraph, QA, SA, binput8, wt_h, QB, SB);    // M2
  k_fusedq<<<EDGES / 32, 128, 0, stream>>>(bgraph, QB, SB, binput8, wt_h, QA, SA);    // M3
  k_fusedq<<<EDGES / 32, 128, 0, stream>>>(bgraph, QA, SA, binput8, wt_h, QB, SB);    // M4
  k_fusedq<<<EDGES / 32, 128, 0, stream>>>(bgraph, QB, SB, binput8, wt_h, QA, SA);    // M5
  k_fusedq<<<EDGES / 32, 128, 0, stream>>>(bgraph, QA, SA, binput8, wt_o, QB, SB);    // M6
  k_atoms<<<NATOMS / 32, 256, 0, stream>>>(fatoms, agraph, QB, SB, Wo, bo, atomh);
  k_pool<<<NMOLS, H, 0, stream>>>(atomh, sstart, slen, out);
}

// Round 12
// 705.289 us; speedup vs baseline: 1.8611x; 1.0265x over previous
//
#include <hip/hip_runtime.h>

#define EDGES 200000
#define NATOMS 100000
#define NMOLS 2000
#define H 128
#define MAXNB 15
#define AFD 18
#define INFD 23
#define LROW 136  // LDS A-tile row stride (bf16): +8 pad, 16B-aligned rows, 2-way banks
#define K1 32     // GEMM1 K (INFD=23 zero-padded to 32)
#define AROW 40   // GEMM1 LDS A-tile row stride (bf16 shorts)

// Precision ledger (measured):
//  R2: e4m3 tables -> err 448 (sat). R3/R4: e5m2 -> 1088/1120 (format-bound).
//  R5-R8: int8 per-32ch block-scale tables + e4m3 binput -> PASS err 136.
//  R9: GEMM1 via bf16 MFMA -> PASS err 128.
// Mechanics ledger (measured):
//  R8: 8 lanes/row uint4 gather -> fusedq ~100us, FETCH 233MB == compulsory floor.
//  R10: launch_bounds(128,8) -> VGPR 32, scratch spill, 2.2x regression.
//  R11: pk-fma + 32b-voffset -> VALUBusy 42.7->33.7 but dur +4us => VALU was
//      NOT the critical path; kernel is latency-bound at ~12-16 waves/CU.
//  R12: revert to R9 bodies; k_fusedq repackaged as 4-wave/256-thread blocks
//      (same per-wave code) to probe a workgroup-slot occupancy cap.

typedef unsigned short bf16s;
typedef unsigned char u8;
typedef __attribute__((ext_vector_type(8))) short short8;
typedef __attribute__((ext_vector_type(4))) float f32x4;
typedef __attribute__((ext_vector_type(2))) float f32x2;
typedef unsigned int uint4u __attribute__((ext_vector_type(4), aligned(4)));

__device__ inline float bf2f(bf16s u) {
  union { unsigned int i; float f; } c; c.i = ((unsigned int)u) << 16; return c.f;
}
__device__ inline bf16s f2bf(float f) {
  union { float f; unsigned int i; } c; c.f = f;
  unsigned int lsb = (c.i >> 16) & 1u;
  c.i += 0x7fffu + lsb;              // round-to-nearest-even
  return (bf16s)(c.i >> 16);
}
__device__ inline unsigned int pack2(f32x2 v) {
  return (unsigned int)f2bf(fmaxf(v.x, 0.f)) |
         ((unsigned int)f2bf(fmaxf(v.y, 0.f)) << 16);
}
// 16-lane max reduce on the VALU pipe via DPP row rotations (ror 1,2,4,8).
#define DPPMAX_STEP(m, CTRL)                                                   \
  {                                                                            \
    int _t = __builtin_amdgcn_update_dpp(                                      \
        0, __builtin_bit_cast(int, m), CTRL, 0xf, 0xf, false);                 \
    m = fmaxf(m, __builtin_bit_cast(float, _t));                               \
  }
__device__ inline float dpp_max16(float m) {
  DPPMAX_STEP(m, 0x121);  // row_ror:1
  DPPMAX_STEP(m, 0x122);  // row_ror:2
  DPPMAX_STEP(m, 0x124);  // row_ror:4
  DPPMAX_STEP(m, 0x128);  // row_ror:8
  return m;
}

// ------- one-time transposed bf16 weights -------
// blk 0: wt_h[n][128] = Wh[k][n];  blk 1: wt_o[n][128] = Wo[AFD+k][n];
// blk 2: wt_i[n][32]  = Wi[k][n] (k<23; zero-pad 23..31)
__global__ __launch_bounds__(256) void k_wt(
    const float* __restrict__ Wh, const float* __restrict__ Wo,
    const float* __restrict__ Wi, bf16s* __restrict__ wt_h,
    bf16s* __restrict__ wt_o, bf16s* __restrict__ wt_i) {
  if (blockIdx.x == 2) {
    for (int i = threadIdx.x; i < H * K1; i += 256) {
      int n = i >> 5, k = i & 31;
      wt_i[i] = (k < INFD) ? f2bf(Wi[k * H + n]) : (bf16s)0;
    }
    return;
  }
  const float* S = blockIdx.x ? (Wo + AFD * H) : Wh;
  bf16s* D = blockIdx.x ? wt_o : wt_h;
  for (int i = threadIdx.x; i < H * H; i += 256) {
    int k = i >> 7, n = i & 127;
    D[n * H + k] = f2bf(S[i]);
  }
}

// MFMA epilogue: 16x128 @ 128x128 from wave-private LDS tile; q8 output:
// int8 payload rows [E][128] (aligned) + per-32ch bf16 scales in [E][4] Sout.
__device__ inline void mfma_epi_q8(const bf16s* Aw, const bf16s* __restrict__ Wt,
                                   u8* __restrict__ P8, bf16s* __restrict__ Sout,
                                   int ebase, int lane) {
  const int mm = lane & 15;
  const int quad = lane >> 4;
  const bf16s* Wp = Wt + (size_t)mm * H + quad * 8;
  const int rbase = ebase + quad * 4;
  f32x4 acc[2][4];
#pragma unroll
  for (int h = 0; h < 2; ++h)
#pragma unroll
    for (int i = 0; i < 4; ++i) acc[h][i] = (f32x4){0.f, 0.f, 0.f, 0.f};
#pragma unroll
  for (int kk = 0; kk < 4; ++kk) {
    short8 af = *(const short8*)&Aw[mm * LROW + quad * 8 + kk * 32];
#pragma unroll
    for (int h = 0; h < 2; ++h)
#pragma unroll
      for (int nt = 0; nt < 4; ++nt) {
        short8 bfr = *(const short8*)(Wp + (size_t)((h * 4 + nt) * 16) * H + kk * 32);
        acc[h][nt] = __builtin_amdgcn_mfma_f32_16x16x32_bf16(af, bfr, acc[h][nt], 0, 0, 0);
      }
  }
  // lane's channel c = (h*4+nt)*16+mm -> 32-ch block b = h*2 + (nt>>1)
  float m[4][4];  // [row i][block b] absmax
#pragma unroll
  for (int i = 0; i < 4; ++i)
#pragma unroll
    for (int b = 0; b < 4; ++b) m[i][b] = 0.f;
#pragma unroll
  for (int h = 0; h < 2; ++h)
#pragma unroll
    for (int nt = 0; nt < 4; ++nt) {
      const int b = h * 2 + (nt >> 1);
#pragma unroll
      for (int i = 0; i < 4; ++i) m[i][b] = fmaxf(m[i][b], fabsf(acc[h][nt][i]));
    }
#pragma unroll
  for (int i = 0; i < 4; ++i)
#pragma unroll
    for (int b = 0; b < 4; ++b) m[i][b] = dpp_max16(m[i][b]);
  float rs[4][4];
  unsigned short sbits[4][4];
#pragma unroll
  for (int i = 0; i < 4; ++i)
#pragma unroll
    for (int b = 0; b < 4; ++b) {
      bf16s sb = f2bf(m[i][b] * (1.f / 127.f));
      float sd = bf2f(sb);  // decode-exact scale
      rs[i][b] = sd > 0.f ? 1.f / sd : 0.f;
      sbits[i][b] = sb;
    }
  if (mm == 0) {
#pragma unroll
    for (int i = 0; i < 4; ++i) {
      ushort4 sv;
      sv.x = sbits[i][0]; sv.y = sbits[i][1];
      sv.z = sbits[i][2]; sv.w = sbits[i][3];
      *(ushort4*)&Sout[(size_t)(rbase + i) * 4] = sv;
    }
  }
#pragma unroll
  for (int h = 0; h < 2; ++h)
#pragma unroll
    for (int nt = 0; nt < 4; ++nt) {
      const int b = h * 2 + (nt >> 1);
#pragma unroll
      for (int i = 0; i < 4; ++i) {
        float q = fminf(fmaxf(acc[h][nt][i] * rs[i][b] + 128.5f, 0.f), 255.f);
        P8[(size_t)(rbase + i) * H + (h * 4 + nt) * 16 + mm] = (u8)(unsigned)q;
      }
    }
}

// ---- binput = fbonds @ W_i via MFMA (e4m3 out); M1 = relu(binput)@W_h (q8) ----
__global__ __launch_bounds__(256) void k_binput_gemm(
    const float* __restrict__ fbonds, const bf16s* __restrict__ wt_i,
    const bf16s* __restrict__ wt_h, u8* __restrict__ binput8,
    u8* __restrict__ P1, bf16s* __restrict__ S1) {
  __shared__ bf16s At[4][16 * AROW];
  __shared__ bf16s Am[4][16 * LROW];
  const int tid = threadIdx.x;
  const int wave = tid >> 6;
  const int lane = tid & 63;
  bf16s* A1 = At[wave];
  bf16s* Aw = Am[wave];
  const int ebase = (blockIdx.x * 4 + wave) * 16;

  // zero the A1 tile (covers the K=23..31 pad), then stage fbonds as bf16
  for (int i = lane; i < 16 * AROW / 2; i += 64) ((unsigned int*)A1)[i] = 0u;
  const float* fb = &fbonds[(size_t)ebase * INFD];
#pragma unroll
  for (int it = 0; it < 6; ++it) {
    int idx = it * 64 + lane;
    if (idx < 16 * INFD) {
      int er = idx / INFD;
      int k = idx - er * INFD;
      A1[er * AROW + k] = f2bf(fb[idx]);
    }
  }
  asm volatile("s_waitcnt lgkmcnt(0)" ::: "memory");

  const int mm = lane & 15;
  const int quad = lane >> 4;
  const int rbase = ebase + quad * 4;
  short8 af = *(const short8*)&A1[mm * AROW + quad * 8];
  const bf16s* Wp = wt_i + mm * K1 + quad * 8;
  f32x4 acc1[8];
#pragma unroll
  for (int nt = 0; nt < 8; ++nt) {
    short8 bfr = *(const short8*)(Wp + (size_t)(nt * 16) * K1);
    acc1[nt] = __builtin_amdgcn_mfma_f32_16x16x32_bf16(
        af, bfr, (f32x4){0.f, 0.f, 0.f, 0.f}, 0, 0, 0);
  }
  // binput8 e4m3 stores + relu->bf16 into GEMM2 A-tile
#pragma unroll
  for (int nt = 0; nt < 8; ++nt) {
#pragma unroll
    for (int i = 0; i < 4; ++i) {
      int d = __builtin_amdgcn_cvt_pk_fp8_f32(acc1[nt][i], acc1[nt][i], 0, false);
      binput8[(size_t)(rbase + i) * H + nt * 16 + mm] = (u8)(d & 0xff);
      Aw[(quad * 4 + i) * LROW + nt * 16 + mm] = f2bf(fmaxf(acc1[nt][i], 0.f));
    }
  }
  asm volatile("s_waitcnt lgkmcnt(0)" ::: "memory");
  mfma_epi_q8(Aw, wt_h, P1, S1, ebase, lane);
}

// ---- fused depth step: Pout = (relu(binput + sum_j P[bgraph[e][j]])) @ Wt ----
// R9 per-wave body; 4 waves per 256-thread block (occupancy probe: if the
// resident-wave cap was workgroup-slot-bound, this doubles waves/CU).
// All tables q8. 8 lanes x 16B (uint4) cover one 128B row; 2 outer iterations.
__global__ __launch_bounds__(256, 4) void k_fusedq(
    const int* __restrict__ bgraph, const u8* __restrict__ P,
    const bf16s* __restrict__ Sin, const u8* __restrict__ binput8,
    const bf16s* __restrict__ Wt, u8* __restrict__ Pout,
    bf16s* __restrict__ Sout) {
  __shared__ bf16s Am[4][16 * LROW];
  const int tid = threadIdx.x;
  const int wave = tid >> 6;
  const int lane = tid & 63;
  bf16s* Aw = Am[wave];
  const int ebase = (blockIdx.x * 4 + wave) * 16;

  const int sub = lane >> 3;   // 8 rows per iteration
  const int col = lane & 7;    // 8 lanes x 16 channels = 128 cols
#pragma unroll
  for (int it = 0; it < 2; ++it) {
    const int erow = it * 8 + sub;
    const int e = ebase + erow;
    const int* bg = &bgraph[(size_t)e * MAXNB];
    uint4u i0 = *(const uint4u*)(bg + 0);
    uint4u i1 = *(const uint4u*)(bg + 4);
    uint4u i2 = *(const uint4u*)(bg + 8);
    int idx[MAXNB];
    idx[0] = i0.x; idx[1] = i0.y; idx[2] = i0.z; idx[3] = i0.w;
    idx[4] = i1.x; idx[5] = i1.y; idx[6] = i1.z; idx[7] = i1.w;
    idx[8] = i2.x; idx[9] = i2.y; idx[10] = i2.z; idx[11] = i2.w;
    idx[12] = bg[12]; idx[13] = bg[13]; idx[14] = bg[14];

    uint4 t[MAXNB];
    float s[MAXNB];
#pragma unroll
    for (int j = 0; j < MAXNB; ++j) {
      t[j] = *(const uint4*)&P[(size_t)idx[j] * H + col * 16];
      s[j] = bf2f(Sin[(size_t)idx[j] * 4 + (col >> 1)]);
    }
    uint4 bi = *(const uint4*)&binput8[(size_t)e * H + col * 16];
    f32x2 acc[8];
    acc[0] = __builtin_amdgcn_cvt_pk_f32_fp8(bi.x, false);
    acc[1] = __builtin_amdgcn_cvt_pk_f32_fp8(bi.x, true);
    acc[2] = __builtin_amdgcn_cvt_pk_f32_fp8(bi.y, false);
    acc[3] = __builtin_amdgcn_cvt_pk_f32_fp8(bi.y, true);
    acc[4] = __builtin_amdgcn_cvt_pk_f32_fp8(bi.z, false);
    acc[5] = __builtin_amdgcn_cvt_pk_f32_fp8(bi.z, true);
    acc[6] = __builtin_amdgcn_cvt_pk_f32_fp8(bi.w, false);
    acc[7] = __builtin_amdgcn_cvt_pk_f32_fp8(bi.w, true);
    float ssum = 0.f;
#pragma unroll
    for (int j = 0; j < MAXNB; ++j) ssum += s[j];
#pragma unroll
    for (int j = 0; j < MAXNB; ++j) {
      const float sj = s[j];
      const unsigned w0 = t[j].x, w1 = t[j].y, w2 = t[j].z, w3 = t[j].w;
      acc[0].x = fmaf(sj, (float)(w0 & 0xffu), acc[0].x);
      acc[0].y = fmaf(sj, (float)((w0 >> 8) & 0xffu), acc[0].y);
      acc[1].x = fmaf(sj, (float)((w0 >> 16) & 0xffu), acc[1].x);
      acc[1].y = fmaf(sj, (float)(w0 >> 24), acc[1].y);
      acc[2].x = fmaf(sj, (float)(w1 & 0xffu), acc[2].x);
      acc[2].y = fmaf(sj, (float)((w1 >> 8) & 0xffu), acc[2].y);
      acc[3].x = fmaf(sj, (float)((w1 >> 16) & 0xffu), acc[3].x);
      acc[3].y = fmaf(sj, (float)(w1 >> 24), acc[3].y);
      acc[4].x = fmaf(sj, (float)(w2 & 0xffu), acc[4].x);
      acc[4].y = fmaf(sj, (float)((w2 >> 8) & 0xffu), acc[4].y);
      acc[5].x = fmaf(sj, (float)((w2 >> 16) & 0xffu), acc[5].x);
      acc[5].y = fmaf(sj, (float)(w2 >> 24), acc[5].y);
      acc[6].x = fmaf(sj, (float)(w3 & 0xffu), acc[6].x);
      acc[6].y = fmaf(sj, (float)((w3 >> 8) & 0xffu), acc[6].y);
      acc[7].x = fmaf(sj, (float)((w3 >> 16) & 0xffu), acc[7].x);
      acc[7].y = fmaf(sj, (float)(w3 >> 24), acc[7].y);
    }
    const float off = 128.f * ssum;
#pragma unroll
    for (int k = 0; k < 8; ++k) { acc[k].x -= off; acc[k].y -= off; }
    uint4 o0, o1;
    o0.x = pack2(acc[0]); o0.y = pack2(acc[1]);
    o0.z = pack2(acc[2]); o0.w = pack2(acc[3]);
    o1.x = pack2(acc[4]); o1.y = pack2(acc[5]);
    o1.z = pack2(acc[6]); o1.w = pack2(acc[7]);
    *(uint4*)&Aw[erow * LROW + col * 16] = o0;
    *(uint4*)&Aw[erow * LROW + col * 16 + 8] = o1;
  }
  asm volatile("s_waitcnt lgkmcnt(0)" ::: "memory");
  mfma_epi_q8(Aw, Wt, Pout, Sout, ebase, lane);
}

// atom_hiddens = relu(fatoms @ Wo[0:18] + sum_j msg[agraph[a][j]] + b_o)
// q8 gather, 8 lanes x 16 channels per atom; 32 atoms per 256-thread block.
__global__ __launch_bounds__(256, 4) void k_atoms(
    const float* __restrict__ fatoms, const int* __restrict__ agraph,
    const u8* __restrict__ msgQ, const bf16s* __restrict__ msgS,
    const float* __restrict__ Wo, const float* __restrict__ bo,
    bf16s* __restrict__ atomh) {
  __shared__ float Wl[AFD * H];
  const int tid = threadIdx.x;
  for (int i = tid; i < AFD * H; i += 256) Wl[i] = Wo[i];
  __syncthreads();
  const int col = tid & 7;
  const int a = blockIdx.x * 32 + (tid >> 3);
  const int* ag = &agraph[(size_t)a * MAXNB];
  uint4u i0 = *(const uint4u*)(ag + 0);
  uint4u i1 = *(const uint4u*)(ag + 4);
  uint4u i2 = *(const uint4u*)(ag + 8);
  int idx[MAXNB];
  idx[0] = i0.x; idx[1] = i0.y; idx[2] = i0.z; idx[3] = i0.w;
  idx[4] = i1.x; idx[5] = i1.y; idx[6] = i1.z; idx[7] = i1.w;
  idx[8] = i2.x; idx[9] = i2.y; idx[10] = i2.z; idx[11] = i2.w;
  idx[12] = ag[12]; idx[13] = ag[13]; idx[14] = ag[14];
  uint4 t[MAXNB];
  float s[MAXNB];
#pragma unroll
  for (int j = 0; j < MAXNB; ++j) {
    t[j] = *(const uint4*)&msgQ[(size_t)idx[j] * H + col * 16];
    s[j] = bf2f(msgS[(size_t)idx[j] * 4 + (col >> 1)]);
  }
  f32x2 acc[8];
#pragma unroll
  for (int k = 0; k < 4; ++k) {
    float4 b = ((const float4*)bo)[col * 4 + k];
    acc[2 * k] = (f32x2){b.x, b.y};
    acc[2 * k + 1] = (f32x2){b.z, b.w};
  }
#pragma unroll
  for (int k = 0; k < AFD; ++k) {
    float f = fatoms[(size_t)a * AFD + k];
#pragma unroll
    for (int q = 0; q < 4; ++q) {
      float4 w = ((const float4*)&Wl[k * H + col * 16])[q];
      acc[2 * q].x = fmaf(f, w.x, acc[2 * q].x);
      acc[2 * q].y = fmaf(f, w.y, acc[2 * q].y);
      acc[2 * q + 1].x = fmaf(f, w.z, acc[2 * q + 1].x);
      acc[2 * q + 1].y = fmaf(f, w.w, acc[2 * q + 1].y);
    }
  }
  float ssum = 0.f;
#pragma unroll
  for (int j = 0; j < MAXNB; ++j) ssum += s[j];
#pragma unroll
  for (int j = 0; j < MAXNB; ++j) {
    const float sj = s[j];
    const unsigned w0 = t[j].x, w1 = t[j].y, w2 = t[j].z, w3 = t[j].w;
    acc[0].x = fmaf(sj, (float)(w0 & 0xffu), acc[0].x);
    acc[0].y = fmaf(sj, (float)((w0 >> 8) & 0xffu), acc[0].y);
    acc[1].x = fmaf(sj, (float)((w0 >> 16) & 0xffu), acc[1].x);
    acc[1].y = fmaf(sj, (float)(w0 >> 24), acc[1].y);
    acc[2].x = fmaf(sj, (float)(w1 & 0xffu), acc[2].x);
    acc[2].y = fmaf(sj, (float)((w1 >> 8) & 0xffu), acc[2].y);
    acc[3].x = fmaf(sj, (float)((w1 >> 16) & 0xffu), acc[3].x);
    acc[3].y = fmaf(sj, (float)(w1 >> 24), acc[3].y);
    acc[4].x = fmaf(sj, (float)(w2 & 0xffu), acc[4].x);
    acc[4].y = fmaf(sj, (float)((w2 >> 8) & 0xffu), acc[4].y);
    acc[5].x = fmaf(sj, (float)((w2 >> 16) & 0xffu), acc[5].x);
    acc[5].y = fmaf(sj, (float)(w2 >> 24), acc[5].y);
    acc[6].x = fmaf(sj, (float)(w3 & 0xffu), acc[6].x);
    acc[6].y = fmaf(sj, (float)((w3 >> 8) & 0xffu), acc[6].y);
    acc[7].x = fmaf(sj, (float)((w3 >> 16) & 0xffu), acc[7].x);
    acc[7].y = fmaf(sj, (float)(w3 >> 24), acc[7].y);
  }
  const float off = 128.f * ssum;
#pragma unroll
  for (int k = 0; k < 8; ++k) { acc[k].x -= off; acc[k].y -= off; }
  uint4 o0, o1;
  o0.x = pack2(acc[0]); o0.y = pack2(acc[1]);
  o0.z = pack2(acc[2]); o0.w = pack2(acc[3]);
  o1.x = pack2(acc[4]); o1.y = pack2(acc[5]);
  o1.z = pack2(acc[6]); o1.w = pack2(acc[7]);
  *(uint4*)&atomh[(size_t)a * H + col * 16] = o0;
  *(uint4*)&atomh[(size_t)a * H + col * 16 + 8] = o1;
}

// ---------------- segment mean pool (bf16 in, f32 out) ----------------
__global__ void k_pool(const bf16s* __restrict__ atomh,
                       const int* __restrict__ sstart, const int* __restrict__ slen,
                       float* __restrict__ out) {
  const int m = blockIdx.x;
  const int c = threadIdx.x;
  const int s = sstart[m];
  const int L = slen[m];
  float sum = 0.f;
  for (int i = 0; i < L; ++i) sum += bf2f(atomh[(size_t)(s + i) * H + c]);
  out[m * H + c] = sum / (float)L;
}

extern "C" void kernel_launch(void* const* d_in, const int* in_sizes, int n_in,
                              void* d_out, int out_size, void* d_ws, size_t ws_size,
                              hipStream_t stream) {
  const float* fatoms = (const float*)d_in[0];
  const float* fbonds = (const float*)d_in[1];
  const int* agraph = (const int*)d_in[2];
  const int* bgraph = (const int*)d_in[3];
  const int* sstart = (const int*)d_in[4];
  const int* slen = (const int*)d_in[5];
  const float* Wi = (const float*)d_in[6];
  const float* Wh = (const float*)d_in[7];
  const float* Wo = (const float*)d_in[8];
  const float* bo = (const float*)d_in[9];
  float* out = (float*)d_out;

  const size_t EH = (size_t)EDGES * H;   // 25.6M bytes for q8 tables
  // Workspace (~81 MB of the budget):
  //  [0,    EH) binput8 e4m3 (dead after M6; atomh bf16 = NATOMS*H*2 = EH overlays)
  //  [EH,  2EH) QA payload | [2EH, 3EH) QB payload
  //  [3EH, ...) SA scales (1.6MB) | SB scales (1.6MB)
  char* W = (char*)d_ws;
  u8*    binput8 = (u8*)W;
  u8*    QA = (u8*)(W + EH);
  u8*    QB = (u8*)(W + 2 * EH);
  bf16s* SA = (bf16s*)(W + 3 * EH);
  bf16s* SB = (bf16s*)(W + 3 * EH + (size_t)EDGES * 8);
  bf16s* atomh = (bf16s*)W;
  bf16s* wt_h = (bf16s*)d_out;   // stashed in d_out; k_pool overwrites later
  bf16s* wt_o = wt_h + H * H;
  bf16s* wt_i = wt_o + H * H;

  k_wt<<<3, 256, 0, stream>>>(Wh, Wo, Wi, wt_h, wt_o, wt_i);
  k_binput_gemm<<<EDGES / 64, 256, 0, stream>>>(fbonds, wt_i, wt_h, binput8, QA, SA); // M1
  k_fusedq<<<EDGES / 64, 256, 0, stream>>>(bgraph, QA, SA, binput8, wt_h, QB, SB);    // M2
  k_fusedq<<<EDGES / 64, 256, 0, stream>>>(bgraph, QB, SB, binput8, wt_h, QA, SA);    // M3
  k_fusedq<<<EDGES / 64, 256, 0, stream>>>(bgraph, QA, SA, binput8, wt_h, QB, SB);    // M4
  k_fusedq<<<EDGES / 64, 256, 0, stream>>>(bgraph, QB, SB, binput8, wt_h, QA, SA);    // M5
  k_fusedq<<<EDGES / 64, 256, 0, stream>>>(bgraph, QA, SA, binput8, wt_o, QB, SB);    // M6
  k_atoms<<<NATOMS / 32, 256, 0, stream>>>(fatoms, agraph, QB, SB, Wo, bo, atomh);
  k_pool<<<NMOLS, H, 0, stream>>>(atomh, sstart, slen, out);
}